// Round 3
// baseline (352.073 us; speedup 1.0000x reference)
//
#include <hip/hip_runtime.h>

typedef unsigned int u32;
typedef float f32x4 __attribute__((ext_vector_type(4)));

#define BB 8
#define SS 2048
#define KK 16
#define RR 16
#define DIN 2048
#define DOUT 2048

// ---------------------------------------------------------------------------
// Kernel 1: mix the banks (all fp32). Unchanged (banks L2-resident, ~5 us).
// ---------------------------------------------------------------------------
__global__ void __launch_bounds__(256) mix_kernel(
    const float* __restrict__ alpha,
    const float* __restrict__ A_bank,
    const float* __restrict__ B_bank,
    float* __restrict__ Am,
    float* __restrict__ Bm)
{
    int t = blockIdx.x * 256 + threadIdx.x;
    const int half = BB * RR * DIN;  // 262144
    if (t < half) {
        int i = t & (DIN - 1);
        int r = (t >> 11) & (RR - 1);
        int b = t >> 15;
        float acc = 0.f;
#pragma unroll
        for (int k = 0; k < KK; ++k)
            acc += alpha[b * KK + k] * A_bank[(k * RR + r) * DIN + i];
        Am[t] = acc;
    } else {
        int u = t - half;
        int r = u & (RR - 1);
        int o = (u >> 4) & (DOUT - 1);
        int b = u >> 15;
        float acc = 0.f;
#pragma unroll
        for (int k = 0; k < KK; ++k)
            acc += alpha[b * KK + k] * B_bank[(k * DOUT + o) * RR + r];
        Bm[u] = acc;
    }
}

// ---------------------------------------------------------------------------
// Kernel 2 (FUSED z + delta): one block owns (b, 16 s-rows). Grid (128,8)
// = 1024 blocks = exactly 4 blocks/CU resident (launch_bounds (256,4)).
//
// ROUND-3 CHANGE (Am -> LDS staging). Round-2 A/B isolated phase-1's
// bottleneck: Am traffic through L1/L2 (rows/wave 4->2 doubled Am traffic,
// +28 us = predicted L1 +13 + L2 +15). Round-1 pushed 512 MB of Am through
// 32 KB L1s (128 KB working set = pure thrash, every read an L2 hit).
// Now each block stages Am[b] through LDS in 8 chunks of [16 r][256 i]
// (16 KB), T14-style: stage loads to regs issued BEFORE the chunk's
// compute (L2 latency hides under FMAs), ds_write after the barrier.
// Am global traffic: 512 MB -> 134 MB (read once per block, L2-resident).
// Per-iter Am reads become conflict-free contiguous ds_read_b128 (LDS pipe,
// overlaps VALU). L1 now carries only h + staging (~270 MB ~= 7 us).
// Phase-1 floor: h HBM stream 134 MB ~= 21 us.
//
// Phase 1 compute (verified round-1 structure): wave owns 4 s rows, lanes
// span i (f32x4, nontemporal h). a[64] accumulators (AGPR-shunted: benign,
// measured rounds 1-2, no scratch). Tree reduction, payload halving: lane l
// ends with z value index l = j*16 + r; zt[wid*64+lane] contiguous store.
//
// Phase 2 (verified round-1 structure): 16 x 2048 delta tile from LDS zt,
// Bm rows in regs, wave-uniform zt broadcasts, nontemporal stores.
// ---------------------------------------------------------------------------
__global__ void __launch_bounds__(256, 4) fused_kernel(
    const float* __restrict__ h,
    const float* __restrict__ Am,
    const float* __restrict__ Bm,
    float* __restrict__ out)
{
    __shared__ float As[16][256];   // Am chunk: 16 KB, single-buffered
    __shared__ float zt[16 * 16];   // z tile: 1 KB

    int b = blockIdx.y;
    int wid = threadIdx.x >> 6;
    int lane = threadIdx.x & 63;
    int s0 = blockIdx.x * 16;             // tile's first s row
    int sw = s0 + wid * 4;                // this wave's first s row

    const float* hb = h + (size_t)b * SS * DIN + (size_t)sw * DIN;
    const float* Ab = Am + (size_t)b * RR * DIN;

    // Staging map: thread t writes As flat floats [t*4 + q*1024] for q=0..3
    // == As[r][io] with r = q*4 + wid, io = lane*4  (1 KB contiguous per
    // wave per q -> conflict-free ds_write_b128; coalesced 1 KB global).
    float* myAsDst = &As[0][0] + (size_t)threadIdx.x * 4;
    const float* myAbSrc = Ab + (size_t)wid * DIN + lane * 4;  // + q*4*DIN + c*256

    float a[64];
#pragma unroll
    for (int v = 0; v < 64; ++v) a[v] = 0.f;

    // Prologue: stage chunk 0.
    f32x4 st[4];
#pragma unroll
    for (int q = 0; q < 4; ++q)
        st[q] = *(const f32x4*)(myAbSrc + (size_t)q * 4 * DIN);
#pragma unroll
    for (int q = 0; q < 4; ++q)
        *(f32x4*)(myAsDst + q * 1024) = st[q];
    __syncthreads();

#pragma unroll 1
    for (int c = 0; c < 8; ++c) {
        int i0 = c * 256 + lane * 4;
        // h loads first (oldest in vmcnt queue: consuming them does not
        // force the younger stage loads to complete).
        f32x4 hv0 = __builtin_nontemporal_load((const f32x4*)(hb + i0));
        f32x4 hv1 = __builtin_nontemporal_load((const f32x4*)(hb + DIN + i0));
        f32x4 hv2 = __builtin_nontemporal_load((const f32x4*)(hb + 2 * DIN + i0));
        f32x4 hv3 = __builtin_nontemporal_load((const f32x4*)(hb + 3 * DIN + i0));
        // T14: issue next chunk's stage loads now; L2 latency hides under
        // this chunk's FMA block. ds_write happens after the barrier.
        if (c < 7) {
#pragma unroll
            for (int q = 0; q < 4; ++q)
                st[q] = *(const f32x4*)(myAbSrc + (size_t)q * 4 * DIN + (c + 1) * 256);
        }
#pragma unroll
        for (int r = 0; r < 16; ++r) {
            f32x4 av = *(const f32x4*)(&As[r][lane * 4]);
            a[0 * 16 + r] += hv0.x * av.x + hv0.y * av.y + hv0.z * av.z + hv0.w * av.w;
            a[1 * 16 + r] += hv1.x * av.x + hv1.y * av.y + hv1.z * av.z + hv1.w * av.w;
            a[2 * 16 + r] += hv2.x * av.x + hv2.y * av.y + hv2.z * av.z + hv2.w * av.w;
            a[3 * 16 + r] += hv3.x * av.x + hv3.y * av.y + hv3.z * av.z + hv3.w * av.w;
        }
        __syncthreads();              // all waves done reading As chunk c
        if (c < 7) {
#pragma unroll
            for (int q = 0; q < 4; ++q)
                *(f32x4*)(myAsDst + q * 1024) = st[q];
        }
        __syncthreads();              // chunk c+1 staged
    }

    // Cross-lane tree reduction, payload halving each step (63 shfl total).
    // lane l ends holding sum over all i of value index l (= j*16 + r).
#pragma unroll
    for (int off = 32; off >= 1; off >>= 1) {
        bool up = (lane & off) != 0;
#pragma unroll
        for (int v = 0; v < off; ++v) {
            float send = up ? a[v] : a[v + off];
            float keep = up ? a[v + off] : a[v];
            a[v] = keep + __shfl_xor(send, off, 64);
        }
    }
    // lane l -> zt[(wid*4 + l/16)*16 + l%16] = zt[wid*64 + l]  (contiguous)
    zt[wid * 64 + lane] = a[0];
    __syncthreads();

    // ------------------- Phase 2: delta tile from LDS z ---------------------
    float* op = out + ((size_t)b * SS + s0) * DOUT;

#pragma unroll 1
    for (int oc = 0; oc < 2; ++oc) {
        int o0 = oc * 1024 + threadIdx.x * 4;
        const float* wp = Bm + ((size_t)b * DOUT + o0) * RR;  // 64 contiguous
        float w[4][16];
#pragma unroll
        for (int j = 0; j < 4; ++j) {
#pragma unroll
            for (int q = 0; q < 4; ++q) {
                f32x4 p = *(const f32x4*)(wp + j * RR + q * 4);
                w[j][q * 4 + 0] = p.x; w[j][q * 4 + 1] = p.y;
                w[j][q * 4 + 2] = p.z; w[j][q * 4 + 3] = p.w;
            }
        }
#pragma unroll 4
        for (int s = 0; s < 16; ++s) {
            // wave-uniform LDS reads -> broadcast, no bank conflicts
            float zz[16];
#pragma unroll
            for (int q = 0; q < 4; ++q) {
                f32x4 zv = *(const f32x4*)(zt + s * 16 + q * 4);
                zz[q * 4 + 0] = zv.x; zz[q * 4 + 1] = zv.y;
                zz[q * 4 + 2] = zv.z; zz[q * 4 + 3] = zv.w;
            }
            float rj[4];
#pragma unroll
            for (int j = 0; j < 4; ++j) {
                float acc = 0.f;
#pragma unroll
                for (int r = 0; r < 16; ++r) acc += w[j][r] * zz[r];
                rj[j] = acc;
            }
            f32x4 res;
            res.x = rj[0]; res.y = rj[1]; res.z = rj[2]; res.w = rj[3];
            __builtin_nontemporal_store(res, (f32x4*)(op + (size_t)s * DOUT + o0));
        }
    }
}

// ---------------------------------------------------------------------------
extern "C" void kernel_launch(void* const* d_in, const int* in_sizes, int n_in,
                              void* d_out, int out_size, void* d_ws, size_t ws_size,
                              hipStream_t stream)
{
    const float* h      = (const float*)d_in[0];   // [B][S][DIN]   fp32
    const float* alpha  = (const float*)d_in[1];   // [B][K]        fp32
    const float* A_bank = (const float*)d_in[2];   // [K][R][DIN]   fp32
    const float* B_bank = (const float*)d_in[3];   // [K][DOUT][R]  fp32
    float* out = (float*)d_out;                    // [B][S][DOUT]  fp32

    // workspace layout (4 MiB total): z not materialized.
    float* Am = (float*)d_ws;                      // [B][R][DIN]  fp32, 2 MiB
    float* Bm = Am + BB * RR * DIN;                // [B][DOUT][R] fp32, 2 MiB

    mix_kernel<<<2048, 256, 0, stream>>>(alpha, A_bank, B_bank, Am, Bm);
    fused_kernel<<<dim3(128, 8), 256, 0, stream>>>(h, Am, Bm, out);
}

// Round 4
// 283.140 us; speedup vs baseline: 1.2435x; 1.2435x over previous
//
#include <hip/hip_runtime.h>

typedef unsigned int u32;
typedef float f32x4 __attribute__((ext_vector_type(4)));

#define BB 8
#define SS 2048
#define KK 16
#define RR 16
#define DIN 2048
#define DOUT 2048

// ---------------------------------------------------------------------------
// Kernel 1: mix the banks (all fp32). Unchanged (banks L2-resident, ~5 us).
// ---------------------------------------------------------------------------
__global__ void __launch_bounds__(256) mix_kernel(
    const float* __restrict__ alpha,
    const float* __restrict__ A_bank,
    const float* __restrict__ B_bank,
    float* __restrict__ Am,
    float* __restrict__ Bm)
{
    int t = blockIdx.x * 256 + threadIdx.x;
    const int half = BB * RR * DIN;  // 262144
    if (t < half) {
        int i = t & (DIN - 1);
        int r = (t >> 11) & (RR - 1);
        int b = t >> 15;
        float acc = 0.f;
#pragma unroll
        for (int k = 0; k < KK; ++k)
            acc += alpha[b * KK + k] * A_bank[(k * RR + r) * DIN + i];
        Am[t] = acc;
    } else {
        int u = t - half;
        int r = u & (RR - 1);
        int o = (u >> 4) & (DOUT - 1);
        int b = u >> 15;
        float acc = 0.f;
#pragma unroll
        for (int k = 0; k < KK; ++k)
            acc += alpha[b * KK + k] * B_bank[(k * DOUT + o) * RR + r];
        Bm[u] = acc;
    }
}

// ---------------------------------------------------------------------------
// Kernel 2 (FUSED z + delta): 2-wave block owns (b, 8 s-rows); wave owns 4.
// Grid (SS/8, B) = (256, 8) = 2048 blocks, 4096 waves -> 4 waves/SIMD.
//
// ROUND-4 CHANGE (a[64] -> a[16] lane remap). Rounds 1-3 isolated phase-1 as
// latency-bound (~59 us vs 21 us h floor): a[64]/lane forced the AGPR shunt
// (VGPR_Count=64 + accvgpr traffic around every FMA) and a 20-load burst per
// coarse chunk at only 3 waves/SIMD. Work per wave is UNCHANGED (4 rows,
// round-2 proved 2 rows/wave doubles Am traffic, +28 us); only the lane
// decomposition changes: lane = rg*16 + il (4 r-groups x 16 i-lanes).
// Lane accumulates 4 rows x 4 r = a[16]. Live set ~95 regs incl explicit
// double-buffered h AND Am prefetch over 32 fine chunks of 64 i -> fits the
// (128,4) cap of 128 with no shunt, no spill. h loads nontemporal (read-once,
// keeps Am/Bm hot); Am/Bm reads cached (L1/L2-resident, 1 MiB each).
//
// Reduction: 4-step halving tree over the 16 i-lanes (xor 8,4,2,1; payload
// 16->1). Lane (rg,il) ends with value il: row = il>>2, r = rg*4 + (il&3).
// zt write is 64 contiguous floats per wave (2 lanes/bank = free).
//
// Phase 2 (verified round-1 structure): 8 x 2048 tile; thread owns 4
// contiguous o per o-chunk (4 chunks); w[4][16] in regs (Bm[b] read once per
// block); zt rows are wave-uniform LDS broadcasts; nontemporal f32x4 stores.
// ---------------------------------------------------------------------------
__global__ void __launch_bounds__(128, 4) fused_kernel(
    const float* __restrict__ h,
    const float* __restrict__ Am,
    const float* __restrict__ Bm,
    float* __restrict__ out)
{
    __shared__ float zt[8 * 16];    // z tile: zt[s_local*16 + r], 512 B

    int b = blockIdx.y;
    int tid = threadIdx.x;
    int wid = tid >> 6;
    int lane = tid & 63;
    int il = lane & 15;             // i-lane within 16-lane group
    int rg = lane >> 4;             // r-group (4 r's per group)
    int s0 = blockIdx.x * 8;        // tile's first s row
    int sw = s0 + wid * 4;          // this wave's first s row

    const float* hl = h + ((size_t)b * SS + sw) * DIN + il * 4;
    const float* al = Am + ((size_t)b * RR + rg * 4) * DIN + il * 4;

    float a[16];
#pragma unroll
    for (int v = 0; v < 16; ++v) a[v] = 0.f;

    // Double-buffered pipeline over 32 chunks of 64 i. Chunk c: lane covers
    // i = c*64 + il*4 .. +3 for 4 rows (h) and its 4 r's (Am).
    f32x4 h0[4], h1[4], av0[4], av1[4];
#pragma unroll
    for (int j = 0; j < 4; ++j)
        h0[j] = __builtin_nontemporal_load((const f32x4*)(hl + (size_t)j * DIN));
#pragma unroll
    for (int q = 0; q < 4; ++q)
        av0[q] = *(const f32x4*)(al + (size_t)q * DIN);

#pragma unroll 1
    for (int c = 0; c < 32; c += 2) {
        // prefetch chunk c+1 while computing chunk c
#pragma unroll
        for (int j = 0; j < 4; ++j)
            h1[j] = __builtin_nontemporal_load((const f32x4*)(hl + (size_t)j * DIN + (c + 1) * 64));
#pragma unroll
        for (int q = 0; q < 4; ++q)
            av1[q] = *(const f32x4*)(al + (size_t)q * DIN + (c + 1) * 64);
#pragma unroll
        for (int q = 0; q < 4; ++q)
#pragma unroll
            for (int j = 0; j < 4; ++j)
                a[j * 4 + q] += h0[j].x * av0[q].x + h0[j].y * av0[q].y +
                                h0[j].z * av0[q].z + h0[j].w * av0[q].w;
        // prefetch chunk c+2 while computing chunk c+1
        if (c + 2 < 32) {
#pragma unroll
            for (int j = 0; j < 4; ++j)
                h0[j] = __builtin_nontemporal_load((const f32x4*)(hl + (size_t)j * DIN + (c + 2) * 64));
#pragma unroll
            for (int q = 0; q < 4; ++q)
                av0[q] = *(const f32x4*)(al + (size_t)q * DIN + (c + 2) * 64);
        }
#pragma unroll
        for (int q = 0; q < 4; ++q)
#pragma unroll
            for (int j = 0; j < 4; ++j)
                a[j * 4 + q] += h1[j].x * av1[q].x + h1[j].y * av1[q].y +
                                h1[j].z * av1[q].z + h1[j].w * av1[q].w;
    }

    // Halving tree over the 16 i-lanes (payload 16 -> 1, 15 shfl).
    // Lane ends with value index il: a[il] = row (il>>2), rq (il&3).
#pragma unroll
    for (int off = 8; off >= 1; off >>= 1) {
        bool up = (il & off) != 0;
#pragma unroll
        for (int v = 0; v < off; ++v) {
            float send = up ? a[v] : a[v + off];
            float keep = up ? a[v + off] : a[v];
            a[v] = keep + __shfl_xor(send, off, 64);
        }
    }
    // row = wid*4 + (il>>2), r = rg*4 + (il&3): per wave 64 contiguous floats
    zt[(wid * 4 + (il >> 2)) * 16 + rg * 4 + (il & 3)] = a[0];
    __syncthreads();

    // ------------------- Phase 2: delta tile from LDS z ---------------------
    float* op = out + ((size_t)b * SS + s0) * DOUT;

#pragma unroll 1
    for (int oc = 0; oc < 4; ++oc) {
        int o0 = oc * 512 + tid * 4;
        const float* wp = Bm + ((size_t)b * DOUT + o0) * RR;  // 64 contiguous
        float w[4][16];
#pragma unroll
        for (int j = 0; j < 4; ++j) {
#pragma unroll
            for (int q = 0; q < 4; ++q) {
                f32x4 p = *(const f32x4*)(wp + j * RR + q * 4);
                w[j][q * 4 + 0] = p.x; w[j][q * 4 + 1] = p.y;
                w[j][q * 4 + 2] = p.z; w[j][q * 4 + 3] = p.w;
            }
        }
#pragma unroll 4
        for (int s = 0; s < 8; ++s) {
            // wave-uniform LDS reads -> broadcast, no bank conflicts
            float zz[16];
#pragma unroll
            for (int q = 0; q < 4; ++q) {
                f32x4 zv = *(const f32x4*)(zt + s * 16 + q * 4);
                zz[q * 4 + 0] = zv.x; zz[q * 4 + 1] = zv.y;
                zz[q * 4 + 2] = zv.z; zz[q * 4 + 3] = zv.w;
            }
            float rj[4];
#pragma unroll
            for (int j = 0; j < 4; ++j) {
                float acc = 0.f;
#pragma unroll
                for (int r = 0; r < 16; ++r) acc += w[j][r] * zz[r];
                rj[j] = acc;
            }
            f32x4 res;
            res.x = rj[0]; res.y = rj[1]; res.z = rj[2]; res.w = rj[3];
            __builtin_nontemporal_store(res, (f32x4*)(op + (size_t)s * DOUT + o0));
        }
    }
}

// ---------------------------------------------------------------------------
extern "C" void kernel_launch(void* const* d_in, const int* in_sizes, int n_in,
                              void* d_out, int out_size, void* d_ws, size_t ws_size,
                              hipStream_t stream)
{
    const float* h      = (const float*)d_in[0];   // [B][S][DIN]   fp32
    const float* alpha  = (const float*)d_in[1];   // [B][K]        fp32
    const float* A_bank = (const float*)d_in[2];   // [K][R][DIN]   fp32
    const float* B_bank = (const float*)d_in[3];   // [K][DOUT][R]  fp32
    float* out = (float*)d_out;                    // [B][S][DOUT]  fp32

    // workspace layout: z not materialized.
    float* Am = (float*)d_ws;                      // [B][R][DIN]  fp32, 1 MiB
    float* Bm = Am + BB * RR * DIN;                // [B][DOUT][R] fp32, 1 MiB

    mix_kernel<<<2048, 256, 0, stream>>>(alpha, A_bank, B_bank, Am, Bm);
    fused_kernel<<<dim3(256, 8), 128, 0, stream>>>(h, Am, Bm, out);
}

// Round 5
// 247.882 us; speedup vs baseline: 1.4203x; 1.1422x over previous
//
#include <hip/hip_runtime.h>

typedef float f32x4 __attribute__((ext_vector_type(4)));

#define BB 8
#define SS 2048
#define KK 16
#define RR 16
#define DIN 2048
#define DOUT 2048

// ---------------------------------------------------------------------------
// Kernel 1: mix the banks (all fp32). Unchanged (banks L2-resident, ~5 us).
// ---------------------------------------------------------------------------
__global__ void __launch_bounds__(256) mix_kernel(
    const float* __restrict__ alpha,
    const float* __restrict__ A_bank,
    const float* __restrict__ B_bank,
    float* __restrict__ Am,
    float* __restrict__ Bm)
{
    int t = blockIdx.x * 256 + threadIdx.x;
    const int half = BB * RR * DIN;  // 262144
    if (t < half) {
        int i = t & (DIN - 1);
        int r = (t >> 11) & (RR - 1);
        int b = t >> 15;
        float acc = 0.f;
#pragma unroll
        for (int k = 0; k < KK; ++k)
            acc += alpha[b * KK + k] * A_bank[(k * RR + r) * DIN + i];
        Am[t] = acc;
    } else {
        int u = t - half;
        int r = u & (RR - 1);
        int o = (u >> 4) & (DOUT - 1);
        int b = u >> 15;
        float acc = 0.f;
#pragma unroll
        for (int k = 0; k < KK; ++k)
            acc += alpha[b * KK + k] * B_bank[(k * DOUT + o) * RR + r];
        Bm[u] = acc;
    }
}

// ---------------------------------------------------------------------------
// global -> LDS async DMA, 16 B per lane. LDS dest is wave-uniform base
// (lane l lands at base + l*16); global src is per-lane. No VGPR round-trip.
// ---------------------------------------------------------------------------
__device__ __forceinline__ void stage16(const float* g, float* l)
{
    __builtin_amdgcn_global_load_lds(
        (const __attribute__((address_space(1))) void*)g,
        (__attribute__((address_space(3))) void*)l, 16, 0, 0);
}

// ---------------------------------------------------------------------------
// Kernel 2 (FUSED z + delta): EXACT round-1 host structure (80 us verified:
// block owns (b, 16 s-rows), wave owns 4 rows, a[64] accumulators, payload-
// halving tree, phase-2 w[4][16]+broadcast) with ONE change:
//
// ROUND-5 CHANGE (Am -> LDS via global_load_lds). Rounds 1/2/4 established
// that fused time tracks L1 load traffic ~1:1 (655MB->80us, 1.05GB->103us,
// 1.17GB->108us): phase 1 is bound by the L1/VMEM service path (20 x 1KB
// load-instrs per wave-chunk, ~16 cyc each), not VALU (27-32%), not HBM
// (h stream ~20 us). The a[64] AGPR shunt is benign (present in all three).
// Fix: Am's 512 MB leaves the VMEM path entirely. Each chunk's 16-row x
// 256-i Am panel (16 KB) is DMA'd global->LDS with global_load_lds width=16
// (async, vmcnt-counted, zero registers - round-3's reg-staging death is
// structurally impossible here). Double-buffered As[2] (32 KB); stage of
// chunk c+1 issues before compute of chunk c and completes under its ~512
// VALU cycles; __syncthreads (vmcnt drain + barrier) publishes it.
// Per-chunk VMEM instrs per wave: 20 -> 8 (4 h NT + 4 stage). Am reads
// become contiguous conflict-free ds_read_b128 (512 MB at 69 TB/s ~ 7 us,
// overlaps VALU). L1 now carries only h (134 MB ~ 3 us of L1 occupancy).
// Phase-1 floor: h HBM stream ~21 us.
//
// Grid (128, 8) = 1024 blocks at 3 blocks/CU (launch_bounds (256,3), the
// round-1-verified register regime): 768 resident + 256 second-generation
// -> read-phase of late blocks overlaps write-phase of early blocks.
// ---------------------------------------------------------------------------
__global__ void __launch_bounds__(256, 3) fused_kernel(
    const float* __restrict__ h,
    const float* __restrict__ Am,
    const float* __restrict__ Bm,
    float* __restrict__ out)
{
    __shared__ float As[2][16][256];   // Am panel double-buffer: 32 KB
    __shared__ float zt[16 * 16];      // z tile: 1 KB

    int b = blockIdx.y;
    int wid = threadIdx.x >> 6;
    int lane = threadIdx.x & 63;
    int s0 = blockIdx.x * 16;             // tile's first s row
    int sw = s0 + wid * 4;                // this wave's first s row

    const float* hb = h + (size_t)b * SS * DIN + (size_t)sw * DIN;
    const float* Ab = Am + (size_t)b * RR * DIN;

    float a[64];
#pragma unroll
    for (int v = 0; v < 64; ++v) a[v] = 0.f;

    // Prologue: stage chunk 0. Wave wid stages rows wid*4..wid*4+3.
#pragma unroll
    for (int q = 0; q < 4; ++q) {
        int r = wid * 4 + q;
        stage16(Ab + (size_t)r * DIN + lane * 4, &As[0][r][0]);
    }
    __syncthreads();

#pragma unroll 1
    for (int c = 0; c < 8; ++c) {
        // Issue next panel's DMA first: lands under this chunk's FMAs.
        if (c < 7) {
#pragma unroll
            for (int q = 0; q < 4; ++q) {
                int r = wid * 4 + q;
                stage16(Ab + (size_t)r * DIN + (c + 1) * 256 + lane * 4,
                        &As[(c + 1) & 1][r][0]);
            }
        }
        int i0 = c * 256 + lane * 4;
        f32x4 hv0 = __builtin_nontemporal_load((const f32x4*)(hb + i0));
        f32x4 hv1 = __builtin_nontemporal_load((const f32x4*)(hb + DIN + i0));
        f32x4 hv2 = __builtin_nontemporal_load((const f32x4*)(hb + 2 * DIN + i0));
        f32x4 hv3 = __builtin_nontemporal_load((const f32x4*)(hb + 3 * DIN + i0));
        const float (*Ac)[256] = As[c & 1];
#pragma unroll
        for (int r = 0; r < 16; ++r) {
            f32x4 av = *(const f32x4*)(&Ac[r][lane * 4]);   // ds_read_b128
            a[0 * 16 + r] += hv0.x * av.x + hv0.y * av.y + hv0.z * av.z + hv0.w * av.w;
            a[1 * 16 + r] += hv1.x * av.x + hv1.y * av.y + hv1.z * av.z + hv1.w * av.w;
            a[2 * 16 + r] += hv2.x * av.x + hv2.y * av.y + hv2.z * av.z + hv2.w * av.w;
            a[3 * 16 + r] += hv3.x * av.x + hv3.y * av.y + hv3.z * av.z + hv3.w * av.w;
        }
        // WAR (done reading As[c&1] before iter c+1 overwrites it) and
        // RAW (stage of c+1 complete: syncthreads drains vmcnt) in one barrier.
        __syncthreads();
    }

    // Cross-lane tree reduction, payload halving each step (63 shfl total).
    // lane l ends holding sum over all i of value index l (= j*16 + r).
#pragma unroll
    for (int off = 32; off >= 1; off >>= 1) {
        bool up = (lane & off) != 0;
#pragma unroll
        for (int v = 0; v < off; ++v) {
            float send = up ? a[v] : a[v + off];
            float keep = up ? a[v + off] : a[v];
            a[v] = keep + __shfl_xor(send, off, 64);
        }
    }
    // lane l -> zt[(wid*4 + l/16)*16 + l%16] = zt[wid*64 + l]  (contiguous)
    zt[wid * 64 + lane] = a[0];
    __syncthreads();

    // ------------------- Phase 2: delta tile from LDS z ---------------------
    float* op = out + ((size_t)b * SS + s0) * DOUT;

#pragma unroll 1
    for (int oc = 0; oc < 2; ++oc) {
        int o0 = oc * 1024 + threadIdx.x * 4;
        const float* wp = Bm + ((size_t)b * DOUT + o0) * RR;  // 64 contiguous
        float w[4][16];
#pragma unroll
        for (int j = 0; j < 4; ++j) {
#pragma unroll
            for (int q = 0; q < 4; ++q) {
                f32x4 p = *(const f32x4*)(wp + j * RR + q * 4);
                w[j][q * 4 + 0] = p.x; w[j][q * 4 + 1] = p.y;
                w[j][q * 4 + 2] = p.z; w[j][q * 4 + 3] = p.w;
            }
        }
#pragma unroll 4
        for (int s = 0; s < 16; ++s) {
            // wave-uniform LDS reads -> broadcast, no bank conflicts
            float zz[16];
#pragma unroll
            for (int q = 0; q < 4; ++q) {
                f32x4 zv = *(const f32x4*)(zt + s * 16 + q * 4);
                zz[q * 4 + 0] = zv.x; zz[q * 4 + 1] = zv.y;
                zz[q * 4 + 2] = zv.z; zz[q * 4 + 3] = zv.w;
            }
            float rj[4];
#pragma unroll
            for (int j = 0; j < 4; ++j) {
                float acc = 0.f;
#pragma unroll
                for (int r = 0; r < 16; ++r) acc += w[j][r] * zz[r];
                rj[j] = acc;
            }
            f32x4 res;
            res.x = rj[0]; res.y = rj[1]; res.z = rj[2]; res.w = rj[3];
            __builtin_nontemporal_store(res, (f32x4*)(op + (size_t)s * DOUT + o0));
        }
    }
}

// ---------------------------------------------------------------------------
extern "C" void kernel_launch(void* const* d_in, const int* in_sizes, int n_in,
                              void* d_out, int out_size, void* d_ws, size_t ws_size,
                              hipStream_t stream)
{
    const float* h      = (const float*)d_in[0];   // [B][S][DIN]   fp32
    const float* alpha  = (const float*)d_in[1];   // [B][K]        fp32
    const float* A_bank = (const float*)d_in[2];   // [K][R][DIN]   fp32
    const float* B_bank = (const float*)d_in[3];   // [K][DOUT][R]  fp32
    float* out = (float*)d_out;                    // [B][S][DOUT]  fp32

    // workspace layout: z not materialized.
    float* Am = (float*)d_ws;                      // [B][R][DIN]  fp32, 1 MiB
    float* Bm = Am + BB * RR * DIN;                // [B][DOUT][R] fp32, 1 MiB

    mix_kernel<<<2048, 256, 0, stream>>>(alpha, A_bank, B_bank, Am, Bm);
    fused_kernel<<<dim3(128, 8), 256, 0, stream>>>(h, Am, Bm, out);
}